// Round 3
// baseline (1683.379 us; speedup 1.0000x reference)
//
#include <hip/hip_runtime.h>
#include <math.h>

typedef __bf16 bf16;
typedef bf16 bf16x8 __attribute__((ext_vector_type(8)));
typedef float f32x4 __attribute__((ext_vector_type(4)));

#define MFMA_BF16(a, b, c) __builtin_amdgcn_mfma_f32_16x16x32_bf16((a), (b), (c), 0, 0, 0)
#define GLDS16(gp, lp)                                                            \
  __builtin_amdgcn_global_load_lds((__attribute__((address_space(1))) void*)(gp), \
                                   (__attribute__((address_space(3))) void*)(lp), 16, 0, 0)
#define VMCNT(N) asm volatile("s_waitcnt vmcnt(" #N ")" ::: "memory")
#define LGKM(N) asm volatile("s_waitcnt lgkmcnt(" #N ")" ::: "memory")
#define SBAR __builtin_amdgcn_s_barrier()
#define SCHED0 __builtin_amdgcn_sched_barrier(0)

static constexpr int kDim   = 512;
static constexpr int kHeads = 16;
static constexpr int kHd    = 32;
static constexpr int kNt    = 64;    // tokens per window (8*8)
static constexpr int kNw    = 49;    // windows per image (7*7)
static constexpr int kL     = 3136;  // 56*56
static constexpr int kToks  = 100352;
static constexpr int kWins  = 1568;
static constexpr int kHid   = 2048;
static constexpr size_t kQS = (size_t)kWins * kHeads * kNt * kHd;  // elems per q/k/v

// ---------------- fp32 -> bf16 weight conversion ----------------
__global__ __launch_bounds__(256) void wconv_kernel(const float* __restrict__ s,
                                                    bf16* __restrict__ d, int n8) {
  int i = blockIdx.x * 256 + threadIdx.x;
  if (i >= n8) return;
  const float4 a = *(const float4*)(s + i * 8);
  const float4 b = *(const float4*)(s + i * 8 + 4);
  bf16x8 o;
  o[0] = (bf16)a.x; o[1] = (bf16)a.y; o[2] = (bf16)a.z; o[3] = (bf16)a.w;
  o[4] = (bf16)b.x; o[5] = (bf16)b.y; o[6] = (bf16)b.z; o[7] = (bf16)b.w;
  *(bf16x8*)(d + i * 8) = o;
}

// ---------------- pos-bias table: (16, 64, 64) fp32 ----------------
__global__ void posbias_kernel(const float* __restrict__ w1, const float* __restrict__ b1,
                               const float* __restrict__ w2, const float* __restrict__ b2,
                               float* __restrict__ tbl) {
  int idx = blockIdx.x * 256 + threadIdx.x;
  if (idx >= kHeads * kNt * kNt) return;
  int h = idx >> 12, n = (idx >> 6) & 63, m = idx & 63;
  float dr = (float)((n >> 3) - (m >> 3));
  float dc = (float)((n & 7) - (m & 7));
  dr = (dr > 0.f ? 1.f : (dr < 0.f ? -1.f : 0.f)) * log1pf(fabsf(dr));
  dc = (dc > 0.f ? 1.f : (dc < 0.f ? -1.f : 0.f)) * log1pf(fabsf(dc));
  float acc = b2[h];
  for (int o = 0; o < 32; ++o) {
    float hv = w1[o * 2] * dr + w1[o * 2 + 1] * dc + b1[o];
    acc += w2[h * 32 + o] * fmaxf(hv, 0.f);
  }
  tbl[idx] = acc;
}

// ---------------- LayerNorm (fp32 in, bf16 out), one wave per token ----------------
// MODE 0: gather (roll -4,-4 + window partition) from x -> xw (window-token order)
// MODE 1: identity token order
template <int MODE>
__global__ __launch_bounds__(256) void ln_kernel(const float* __restrict__ x,
                                                 const float* __restrict__ g,
                                                 const float* __restrict__ be,
                                                 bf16* __restrict__ o) {
  const int t = blockIdx.x * 4 + (threadIdx.x >> 6);
  const int lane = threadIdx.x & 63;
  size_t src;
  if (MODE == 0) {
    const int win = t >> 6, n = t & 63;
    const int b = win / kNw, wi = win % kNw;
    const int h0 = ((wi / 7) * 8 + (n >> 3) + 4) % 56;   // roll(-4): src = dst+4 mod 56
    const int w0 = ((wi % 7) * 8 + (n & 7) + 4) % 56;
    src = ((size_t)b * kL + h0 * 56 + w0) * kDim;
  } else {
    src = (size_t)t * kDim;
  }
  const float4 a = *(const float4*)(x + src + lane * 8);
  const float4 bq = *(const float4*)(x + src + lane * 8 + 4);
  float xf[8] = {a.x, a.y, a.z, a.w, bq.x, bq.y, bq.z, bq.w};
  float s = 0.f, s2 = 0.f;
#pragma unroll
  for (int j = 0; j < 8; ++j) { s += xf[j]; s2 += xf[j] * xf[j]; }
#pragma unroll
  for (int off = 32; off > 0; off >>= 1) { s += __shfl_xor(s, off); s2 += __shfl_xor(s2, off); }
  const float mean = s * (1.f / 512.f);
  const float rstd = rsqrtf(s2 * (1.f / 512.f) - mean * mean + 1e-5f);
  const float4 ga = *(const float4*)(g + lane * 8);
  const float4 gb = *(const float4*)(g + lane * 8 + 4);
  const float4 ba = *(const float4*)(be + lane * 8);
  const float4 bb = *(const float4*)(be + lane * 8 + 4);
  const float gv[8] = {ga.x, ga.y, ga.z, ga.w, gb.x, gb.y, gb.z, gb.w};
  const float bv[8] = {ba.x, ba.y, ba.z, ba.w, bb.x, bb.y, bb.z, bb.w};
  bf16x8 ov;
#pragma unroll
  for (int j = 0; j < 8; ++j) ov[j] = (bf16)((xf[j] - mean) * rstd * gv[j] + bv[j]);
  *(bf16x8*)(o + (size_t)t * kDim + lane * 8) = ov;
}

// ---------------- GEMM 256x256, BK=64, 8 waves, fully pipelined ----------------
// C[M,N] = A[M,K] * B[N,K]^T + bias, fused epilogues.
// LDS: [buf][A/B][khalf][256 rows x 32 cols], 16B slots XOR-swizzled (see R0 notes);
// staging = linear-dest global_load_lds with inverse swizzle on global source addr.
// NEW (R3): register-fragment pipeline one phase ahead with COUNTED lgkmcnt, so the
// LDS-read pipe fills during MFMA instead of serializing at the barrier.
//   ph1: rd(af1<-cb.k0.mhi) | GLDS A.k0' | lgkm(4) | MFMA(mlo,af0,bfr0) | vmcnt(2) | bar
//   ph2: rd(af0<-cb.k1.mlo, bfr1<-cb.k1) | GLDS B.k0' | lgkm(8) | MFMA(mhi,af1,bfr0) | bar
//   ph3: rd(af1<-cb.k1.mhi) | GLDS A.k1' | lgkm(4) | MFMA(mlo,af0,bfr1) | vmcnt(2) | bar
//   ph4: rd(af0<-nb.k0.mlo, bfr0<-nb.k0) | GLDS B.k1' | lgkm(8) | MFMA(mhi,af1,bfr1) | bar
// vmcnt(2) @ph1-end publishes k1(t) (read from ph2 on); vmcnt(2) @ph3-end publishes
// k0(t+1) (read from ph4 on). Per-wave GLDS in flight never exceeds 6; never drained to 0.
#define LOAD_A(dst, CB, KH, MB)                                        \
  _Pragma("unroll") for (int i = 0; i < 4; ++i)                        \
      dst[i] = *(const bf16x8*)(&L[CB][0][KH][aoff + (MB + i) * 512]);
#define LOAD_B(dst, CB, KH)                                            \
  _Pragma("unroll") for (int i = 0; i < 4; ++i)                        \
      dst[i] = *(const bf16x8*)(&L[CB][1][KH][boff + i * 512]);
#define MFMAS(MB, AF, BF)                                              \
  SCHED0;                                                              \
  __builtin_amdgcn_s_setprio(1);                                       \
  _Pragma("unroll") for (int mi = 0; mi < 4; ++mi)                     \
  _Pragma("unroll") for (int ni = 0; ni < 4; ++ni)                     \
      acc[MB + mi][ni] = MFMA_BF16(AF[mi], BF[ni], acc[MB + mi][ni]);  \
  __builtin_amdgcn_s_setprio(0)

template <int EPI>
__global__ __launch_bounds__(512, 2) void gemm256(const bf16* __restrict__ A, const bf16* __restrict__ B,
                                                  const float* __restrict__ bias, void* __restrict__ Cv,
                                                  const float* __restrict__ extra, int N, int K) {
  __shared__ __align__(16) bf16 L[2][2][2][8192];  // 128 KiB
  const int nbn = N >> 8;
  const int nwg = (int)gridDim.x;
  int wg = (int)blockIdx.x;
  {  // bijective XCD-aware swizzle (m204)
    const int q = nwg >> 3, r = nwg & 7;
    const int xcd = wg & 7, loc = wg >> 3;
    wg = (xcd < r ? xcd * (q + 1) : r * (q + 1) + (xcd - r) * q) + loc;
  }
  const int bm = wg / nbn, bn = wg % nbn;
  const int tid = (int)threadIdx.x;
  const int wave = tid >> 6, lane = tid & 63;
  const int wm2 = wave >> 2, wn4 = wave & 3;       // 2 (M) x 4 (N) wave grid
  const int quad = lane >> 4, l16 = lane & 15;

  // staging source mapping: inverse swizzle of linear dest slot, 2 issues/thread
  const int sl0 = tid, sl1 = 512 + tid;
  const int rp0 = sl0 >> 3, ls0 = (sl0 & 7) ^ (rp0 & 7);
  const int rp1 = sl1 >> 3, ls1 = (sl1 & 7) ^ (rp1 & 7);
  const int row0 = rp0 * 2 + (ls0 >> 2), c0 = ls0 & 3;
  const int row1 = rp1 * 2 + (ls1 >> 2), c1 = ls1 & 3;
  const bf16* pa0 = A + (size_t)(bm * 256 + row0) * K + c0 * 8;
  const bf16* pa1 = A + (size_t)(bm * 256 + row1) * K + c1 * 8;
  const bf16* pb0 = B + (size_t)(bn * 256 + row0) * K + c0 * 8;
  const bf16* pb1 = B + (size_t)(bn * 256 + row1) * K + c1 * 8;

  // ds_read fragment offsets (elems); +512 per 16-row step (swizzle-invariant)
  const int ar = wm2 * 128 + l16, arp = ar >> 1;
  const int aoff = (arp * 8 + ((((ar & 1) << 2) | quad) ^ (arp & 7))) * 8;
  const int br = wn4 * 64 + l16, brp = br >> 1;
  const int boff = (brp * 8 + ((((br & 1) << 2) | quad) ^ (brp & 7))) * 8;

  f32x4 acc[8][4] = {};
  bf16x8 af0[4], af1[4], bfr0[4], bfr1[4];

  // prologue: stage tile 0 -> buf 0, order [A.k0, B.k0, A.k1, B.k1]
  GLDS16(pa0, &L[0][0][0][sl0 * 8]);
  GLDS16(pa1, &L[0][0][0][sl1 * 8]);
  GLDS16(pb0, &L[0][1][0][sl0 * 8]);
  GLDS16(pb1, &L[0][1][0][sl1 * 8]);
  GLDS16(pa0 + 32, &L[0][0][1][sl0 * 8]);
  GLDS16(pa1 + 32, &L[0][0][1][sl1 * 8]);
  GLDS16(pb0 + 32, &L[0][1][1][sl0 * 8]);
  GLDS16(pb1 + 32, &L[0][1][1][sl1 * 8]);
  VMCNT(4);  // A.k0, B.k0 of tile 0 resident (own shares)
  SBAR;      // ... for everyone
  // preload phase-1 regs (8 reads left in flight; ph1 waits lgkm(4) after issuing 4)
  LOAD_A(af0, 0, 0, 0);
  LOAD_B(bfr0, 0, 0);

#pragma unroll 2
  for (int kt = 0; kt < K; kt += 64) {
    const int cb = (kt >> 6) & 1, nb = cb ^ 1;
    const int kn = (kt + 64 < K) ? (kt + 64) : kt;  // clamp: dead restage on last tile
    // ---- phase 1 ----
    LOAD_A(af1, cb, 0, 4);
    GLDS16(pa0 + kn, &L[nb][0][0][sl0 * 8]);
    GLDS16(pa1 + kn, &L[nb][0][0][sl1 * 8]);
    LGKM(4);
    MFMAS(0, af0, bfr0);
    VMCNT(2);  // k1(t) resident
    SBAR;
    // ---- phase 2 ----
    LOAD_A(af0, cb, 1, 0);
    LOAD_B(bfr1, cb, 1);
    GLDS16(pb0 + kn, &L[nb][1][0][sl0 * 8]);
    GLDS16(pb1 + kn, &L[nb][1][0][sl1 * 8]);
    LGKM(8);
    MFMAS(4, af1, bfr0);
    SBAR;
    // ---- phase 3 ----
    LOAD_A(af1, cb, 1, 4);
    GLDS16(pa0 + kn + 32, &L[nb][0][1][sl0 * 8]);
    GLDS16(pa1 + kn + 32, &L[nb][0][1][sl1 * 8]);
    LGKM(4);
    MFMAS(0, af0, bfr1);
    VMCNT(2);  // k0(t+1) resident
    SBAR;
    // ---- phase 4 ----
    LOAD_A(af0, nb, 0, 0);
    LOAD_B(bfr0, nb, 0);
    GLDS16(pb0 + kn + 32, &L[nb][1][1][sl0 * 8]);
    GLDS16(pb1 + kn + 32, &L[nb][1][1][sl1 * 8]);
    LGKM(8);
    MFMAS(4, af1, bfr1);
    SBAR;
  }

  // epilogue: C layout col=lane&15, row=quad*4+reg  [m89/m91]
  bf16* Cb = (bf16*)Cv;
  float* Cf = (float*)Cv;
#pragma unroll
  for (int mi = 0; mi < 8; ++mi) {
#pragma unroll
    for (int ni = 0; ni < 4; ++ni) {
      const int col = bn * 256 + wn4 * 64 + ni * 16 + l16;
      const float bb = bias[col];
#pragma unroll
      for (int r = 0; r < 4; ++r) {
        const int row = bm * 256 + wm2 * 128 + mi * 16 + quad * 4 + r;
        float val = acc[mi][ni][r] + bb;
        if constexpr (EPI == 1) {
          const int which = col >> 9, head = (col >> 5) & 15, d = col & 31;
          const int win = row >> 6, n = row & 63;
          Cb[(size_t)which * kQS + (((size_t)win * kHeads + head) * kNt + n) * kHd + d] = (bf16)val;
        } else if constexpr (EPI == 2) {
          val = 0.5f * val * (1.f + erff(val * 0.70710678118654752f));
          Cb[(size_t)row * N + col] = (bf16)val;
        } else if constexpr (EPI == 3) {
          Cf[(size_t)row * N + col] = val + extra[(size_t)row * N + col];
        } else {  // EPI == 4
          const int win = row >> 6, n = row & 63;
          const int b = win / kNw, wi = win % kNw;
          const int h0 = ((wi / 7) * 8 + (n >> 3) + 4) % 56;  // roll back (+4)
          const int w0 = ((wi % 7) * 8 + (n & 7) + 4) % 56;
          const size_t dst = ((size_t)b * kL + h0 * 56 + w0) * kDim + col;
          Cf[dst] = val + extra[dst];
        }
      }
    }
  }
}

// ---------------- attention: one wave per (window, head) ----------------
__device__ __forceinline__ int reg3(int x) { return x < 48 ? 0 : (x < 52 ? 1 : 2); }

__global__ __launch_bounds__(128) void attn_kernel(const bf16* __restrict__ qkv,
                                                   const float* __restrict__ ptbl,
                                                   bf16* __restrict__ out) {
  __shared__ float Sb[2][64 * 65];
  __shared__ float Rs[2][64];
  __shared__ bf16  Pb[2][64 * 72];
  __shared__ bf16  Vt[2][32 * 72];
  const int w = threadIdx.x >> 6, lane = threadIdx.x & 63;
  const int gwh = blockIdx.x * 2 + w;
  const int win = gwh >> 4, h = gwh & 15;
  const int quad = lane >> 4, l16 = lane & 15;
  const bf16* q = qkv + ((size_t)win * kHeads + h) * (kNt * kHd);
  const bf16* k = q + kQS;
  const bf16* v = q + 2 * kQS;

  // stage V^T (Vt[d][tok], pitch 72)
#pragma unroll
  for (int i = 0; i < 4; ++i) {
    const int row = i * 16 + (lane >> 2);
    const int d0 = (lane & 3) * 8;
    bf16x8 vv = *(const bf16x8*)(v + row * kHd + d0);
#pragma unroll
    for (int j = 0; j < 8; ++j) Vt[w][(d0 + j) * 72 + row] = vv[j];
  }

  // S = Q K^T: hd=32 == MFMA K, frags straight from global
  bf16x8 qf[4], kf[4];
#pragma unroll
  for (int i = 0; i < 4; ++i) qf[i] = *(const bf16x8*)(q + (i * 16 + l16) * kHd + quad * 8);
#pragma unroll
  for (int j = 0; j < 4; ++j) kf[j] = *(const bf16x8*)(k + (j * 16 + l16) * kHd + quad * 8);
  f32x4 sa[4][4] = {};
#pragma unroll
  for (int i = 0; i < 4; ++i)
#pragma unroll
    for (int j = 0; j < 4; ++j) sa[i][j] = MFMA_BF16(qf[i], kf[j], sa[i][j]);

  // scale + pos-bias + shift-mask, write S (fp32, pitch 65 -> conflict-free row reads)
  const int wi = win % kNw;
  const int hb = (wi / 7) * 8, wb = (wi % 7) * 8;
  const float* bh = ptbl + h * 4096;
#pragma unroll
  for (int i = 0; i < 4; ++i) {
#pragma unroll
    for (int j = 0; j < 4; ++j) {
      const int ct = j * 16 + l16;
      const int crg = reg3(hb + (ct >> 3)) * 3 + reg3(wb + (ct & 7));
#pragma unroll
      for (int r = 0; r < 4; ++r) {
        const int rt = i * 16 + quad * 4 + r;
        const int rrg = reg3(hb + (rt >> 3)) * 3 + reg3(wb + (rt & 7));
        float sv = sa[i][j][r] * 0.17677669529663687f + bh[rt * 64 + ct];
        if (rrg != crg) sv -= 100.f;
        Sb[w][rt * 65 + ct] = sv;
      }
    }
  }
  __syncthreads();

  // softmax: one row per lane; store unnormalized P (bf16), normalize O at the end
  float mx = -1e30f;
  for (int i = 0; i < 64; ++i) mx = fmaxf(mx, Sb[w][lane * 65 + i]);
  float sum = 0.f;
  for (int i = 0; i < 64; ++i) {
    const float p = __expf(Sb[w][lane * 65 + i] - mx);
    sum += p;
    Pb[w][lane * 72 + i] = (bf16)p;
  }
  Rs[w][lane] = 1.f / sum;
  __syncthreads();

  // O = P V
  f32x4 oa[4][2] = {};
#pragma unroll
  for (int kk = 0; kk < 2; ++kk) {
    bf16x8 pf[4], vf[2];
#pragma unroll
    for (int mi = 0; mi < 4; ++mi)
      pf[mi] = *(const bf16x8*)(&Pb[w][(mi * 16 + l16) * 72 + kk * 32 + quad * 8]);
#pragma unroll
    for (int nj = 0; nj < 2; ++nj)
      vf[nj] = *(const bf16x8*)(&Vt[w][(nj * 16 + l16) * 72 + kk * 32 + quad * 8]);
#pragma unroll
    for (int mi = 0; mi < 4; ++mi)
#pragma unroll
      for (int nj = 0; nj < 2; ++nj) oa[mi][nj] = MFMA_BF16(pf[mi], vf[nj], oa[mi][nj]);
  }
#pragma unroll
  for (int mi = 0; mi < 4; ++mi)
#pragma unroll
    for (int nj = 0; nj < 2; ++nj)
#pragma unroll
      for (int r = 0; r < 4; ++r) {
        const int row = mi * 16 + quad * 4 + r;
        const int col = nj * 16 + l16;
        out[((size_t)win * kNt + row) * kDim + h * kHd + col] = (bf16)(oa[mi][nj][r] * Rs[w][row]);
      }
}

// ---------------- launch ----------------
extern "C" void kernel_launch(void* const* d_in, const int* in_sizes, int n_in,
                              void* d_out, int out_size, void* d_ws, size_t ws_size,
                              hipStream_t stream) {
  (void)in_sizes; (void)n_in; (void)out_size; (void)ws_size;
  const float* x      = (const float*)d_in[0];
  const float* g1     = (const float*)d_in[1];
  const float* be1    = (const float*)d_in[2];
  const float* w_qkv  = (const float*)d_in[3];
  const float* b_qkv  = (const float*)d_in[4];
  const float* pm_w1  = (const float*)d_in[5];
  const float* pm_b1  = (const float*)d_in[6];
  const float* pm_w2  = (const float*)d_in[7];
  const float* pm_b2  = (const float*)d_in[8];
  const float* w_proj = (const float*)d_in[9];
  const float* b_proj = (const float*)d_in[10];
  const float* g2     = (const float*)d_in[11];
  const float* be2    = (const float*)d_in[12];
  const float* w_fc1  = (const float*)d_in[13];
  const float* b_fc1  = (const float*)d_in[14];
  const float* w_fc2  = (const float*)d_in[15];
  const float* b_fc2  = (const float*)d_in[16];
  float* out = (float*)d_out;
  char* ws = (char*)d_ws;

  // workspace layout (bytes); regions reused across phases
  constexpr size_t OFF_WB   = 1u << 20;                 // bf16 weights (8 MiB region)
  constexpr size_t OFF_XW   = OFF_WB + (8u << 20);      // xw -> attn_out -> xn2 (bf16, 103 MB)
  constexpr size_t SZ_ACT   = (size_t)kToks * kDim * 2;
  constexpr size_t OFF_QKV  = OFF_XW + SZ_ACT;          // qkv bf16 (308 MB) -> x1 fp32 + hbuf bf16
  float* biastbl = (float*)ws;
  bf16* wqb = (bf16*)(ws + OFF_WB);                     // 786432 elems
  bf16* wpb = wqb + 786432;                             // 262144
  bf16* w1b = wpb + 262144;                             // 1048576
  bf16* w2b = w1b + 1048576;                            // 1048576
  bf16* xw    = (bf16*)(ws + OFF_XW);
  bf16* attnb = xw;            // after QKV gemm consumes xw
  bf16* xn2   = xw;            // after proj consumes attnb
  bf16* qkvb = (bf16*)(ws + OFF_QKV);
  float* x1  = (float*)(ws + OFF_QKV);                  // after attn consumes qkv (206 MB)
  bf16* hbuf = (bf16*)(ws + OFF_QKV + (size_t)kToks * kDim * 4);  // 103 MB

  wconv_kernel<<<dim3(786432 / 2048), dim3(256), 0, stream>>>(w_qkv, wqb, 786432 / 8);
  wconv_kernel<<<dim3(262144 / 2048), dim3(256), 0, stream>>>(w_proj, wpb, 262144 / 8);
  wconv_kernel<<<dim3(1048576 / 2048), dim3(256), 0, stream>>>(w_fc1, w1b, 1048576 / 8);
  wconv_kernel<<<dim3(1048576 / 2048), dim3(256), 0, stream>>>(w_fc2, w2b, 1048576 / 8);
  posbias_kernel<<<dim3(256), dim3(256), 0, stream>>>(pm_w1, pm_b1, pm_w2, pm_b2, biastbl);
  ln_kernel<0><<<dim3(kToks / 4), dim3(256), 0, stream>>>(x, g1, be1, xw);
  gemm256<1><<<dim3((kToks / 256) * (1536 / 256)), dim3(512), 0, stream>>>(
      xw, wqb, b_qkv, qkvb, nullptr, 1536, 512);
  attn_kernel<<<dim3(kWins * kHeads / 2), dim3(128), 0, stream>>>(qkvb, biastbl, attnb);
  gemm256<4><<<dim3((kToks / 256) * (512 / 256)), dim3(512), 0, stream>>>(
      attnb, wpb, b_proj, x1, x, 512, 512);
  ln_kernel<1><<<dim3(kToks / 4), dim3(256), 0, stream>>>(x1, g2, be2, xn2);
  constexpr int kChunk = kToks / 4;  // 25088 rows per MLP chunk
  for (int c = 0; c < 4; ++c) {
    const size_t ro = (size_t)c * kChunk * kDim;
    gemm256<2><<<dim3((kChunk / 256) * (kHid / 256)), dim3(512), 0, stream>>>(
        xn2 + ro, w1b, b_fc1, hbuf, nullptr, kHid, 512);
    gemm256<3><<<dim3((kChunk / 256) * (512 / 256)), dim3(512), 0, stream>>>(
        hbuf, w2b, b_fc2, out + ro, x1 + ro, 512, kHid);
  }
}

// Round 4
// 1673.715 us; speedup vs baseline: 1.0058x; 1.0058x over previous
//
#include <hip/hip_runtime.h>
#include <math.h>

typedef __bf16 bf16;
typedef bf16 bf16x4 __attribute__((ext_vector_type(4)));
typedef bf16 bf16x8 __attribute__((ext_vector_type(8)));
typedef float f32x4 __attribute__((ext_vector_type(4)));

#define MFMA_BF16(a, b, c) __builtin_amdgcn_mfma_f32_16x16x32_bf16((a), (b), (c), 0, 0, 0)
#define GLDS16(gp, lp)                                                            \
  __builtin_amdgcn_global_load_lds((__attribute__((address_space(1))) void*)(gp), \
                                   (__attribute__((address_space(3))) void*)(lp), 16, 0, 0)
#define VMCNT(N) asm volatile("s_waitcnt vmcnt(" #N ")" ::: "memory")
#define LGKM(N) asm volatile("s_waitcnt lgkmcnt(" #N ")" ::: "memory")
#define SBAR __builtin_amdgcn_s_barrier()
#define SCHED0 __builtin_amdgcn_sched_barrier(0)

static constexpr int kDim   = 512;
static constexpr int kHeads = 16;
static constexpr int kHd    = 32;
static constexpr int kNt    = 64;    // tokens per window (8*8)
static constexpr int kNw    = 49;    // windows per image (7*7)
static constexpr int kL     = 3136;  // 56*56
static constexpr int kToks  = 100352;
static constexpr int kWins  = 1568;
static constexpr int kHid   = 2048;
static constexpr size_t kQS = (size_t)kWins * kHeads * kNt * kHd;  // elems per q/k/v

// ---------------- fp32 -> bf16 weight conversion ----------------
__global__ __launch_bounds__(256) void wconv_kernel(const float* __restrict__ s,
                                                    bf16* __restrict__ d, int n8) {
  int i = blockIdx.x * 256 + threadIdx.x;
  if (i >= n8) return;
  const float4 a = *(const float4*)(s + i * 8);
  const float4 b = *(const float4*)(s + i * 8 + 4);
  bf16x8 o;
  o[0] = (bf16)a.x; o[1] = (bf16)a.y; o[2] = (bf16)a.z; o[3] = (bf16)a.w;
  o[4] = (bf16)b.x; o[5] = (bf16)b.y; o[6] = (bf16)b.z; o[7] = (bf16)b.w;
  *(bf16x8*)(d + i * 8) = o;
}

// ---------------- pos-bias table: (16, 64, 64) fp32 ----------------
__global__ void posbias_kernel(const float* __restrict__ w1, const float* __restrict__ b1,
                               const float* __restrict__ w2, const float* __restrict__ b2,
                               float* __restrict__ tbl) {
  int idx = blockIdx.x * 256 + threadIdx.x;
  if (idx >= kHeads * kNt * kNt) return;
  int h = idx >> 12, n = (idx >> 6) & 63, m = idx & 63;
  float dr = (float)((n >> 3) - (m >> 3));
  float dc = (float)((n & 7) - (m & 7));
  dr = (dr > 0.f ? 1.f : (dr < 0.f ? -1.f : 0.f)) * log1pf(fabsf(dr));
  dc = (dc > 0.f ? 1.f : (dc < 0.f ? -1.f : 0.f)) * log1pf(fabsf(dc));
  float acc = b2[h];
  for (int o = 0; o < 32; ++o) {
    float hv = w1[o * 2] * dr + w1[o * 2 + 1] * dc + b1[o];
    acc += w2[h * 32 + o] * fmaxf(hv, 0.f);
  }
  tbl[idx] = acc;
}

// ---------------- LayerNorm (fp32 in, bf16 out), one wave per token ----------------
// MODE 0: gather (roll -4,-4 + window partition) from x -> xw (window-token order)
// MODE 1: identity token order
template <int MODE>
__global__ __launch_bounds__(256) void ln_kernel(const float* __restrict__ x,
                                                 const float* __restrict__ g,
                                                 const float* __restrict__ be,
                                                 bf16* __restrict__ o) {
  const int t = blockIdx.x * 4 + (threadIdx.x >> 6);
  const int lane = threadIdx.x & 63;
  size_t src;
  if (MODE == 0) {
    const int win = t >> 6, n = t & 63;
    const int b = win / kNw, wi = win % kNw;
    const int h0 = ((wi / 7) * 8 + (n >> 3) + 4) % 56;   // roll(-4): src = dst+4 mod 56
    const int w0 = ((wi % 7) * 8 + (n & 7) + 4) % 56;
    src = ((size_t)b * kL + h0 * 56 + w0) * kDim;
  } else {
    src = (size_t)t * kDim;
  }
  const float4 a = *(const float4*)(x + src + lane * 8);
  const float4 bq = *(const float4*)(x + src + lane * 8 + 4);
  float xf[8] = {a.x, a.y, a.z, a.w, bq.x, bq.y, bq.z, bq.w};
  float s = 0.f, s2 = 0.f;
#pragma unroll
  for (int j = 0; j < 8; ++j) { s += xf[j]; s2 += xf[j] * xf[j]; }
#pragma unroll
  for (int off = 32; off > 0; off >>= 1) { s += __shfl_xor(s, off); s2 += __shfl_xor(s2, off); }
  const float mean = s * (1.f / 512.f);
  const float rstd = rsqrtf(s2 * (1.f / 512.f) - mean * mean + 1e-5f);
  const float4 ga = *(const float4*)(g + lane * 8);
  const float4 gb = *(const float4*)(g + lane * 8 + 4);
  const float4 ba = *(const float4*)(be + lane * 8);
  const float4 bb = *(const float4*)(be + lane * 8 + 4);
  const float gv[8] = {ga.x, ga.y, ga.z, ga.w, gb.x, gb.y, gb.z, gb.w};
  const float bv[8] = {ba.x, ba.y, ba.z, ba.w, bb.x, bb.y, bb.z, bb.w};
  bf16x8 ov;
#pragma unroll
  for (int j = 0; j < 8; ++j) ov[j] = (bf16)((xf[j] - mean) * rstd * gv[j] + bv[j]);
  *(bf16x8*)(o + (size_t)t * kDim + lane * 8) = ov;
}

// ---------------- GEMM 256x256, BK=64, 8 waves, pipelined, transposed-acc epilogue --------
// C[M,N] = A[M,K] * B[N,K]^T + bias, fused epilogues.
// LDS: [buf][A/B][khalf][256 rows x 32 cols], 16B slots XOR-swizzled; staging is
// linear-dest global_load_lds with inverse swizzle on the global source address.
// R3: register-fragment pipeline one phase ahead with COUNTED lgkmcnt; counted vmcnt.
// R4: (a) MFMA operand SWAP — mfma(bfr, af): D rows = N-dim, so each thread's 4 acc
//     regs are 4 CONSECUTIVE OUTPUT FEATURES at one token -> 8B/16B vector stores,
//     float4 bias/extra loads (4x fewer epilogue memory instructions).
//     row(token) = ... + mi*16 + l16 ; col(feature) = ... + ni*16 + quad*4 + r.
//     (b) last K-tile peeled: no dead restage; VMCNT(0) drain there keeps counts exact.
#define LOAD_A(dst, CB, KH, MB)                                        \
  _Pragma("unroll") for (int i = 0; i < 4; ++i)                        \
      dst[i] = *(const bf16x8*)(&L[CB][0][KH][aoff + (MB + i) * 512]);
#define LOAD_B(dst, CB, KH)                                            \
  _Pragma("unroll") for (int i = 0; i < 4; ++i)                        \
      dst[i] = *(const bf16x8*)(&L[CB][1][KH][boff + i * 512]);
#define MFMAS(MB, AF, BF)                                              \
  SCHED0;                                                              \
  __builtin_amdgcn_s_setprio(1);                                       \
  _Pragma("unroll") for (int mi = 0; mi < 4; ++mi)                     \
  _Pragma("unroll") for (int ni = 0; ni < 4; ++ni)                     \
      acc[MB + mi][ni] = MFMA_BF16(BF[ni], AF[mi], acc[MB + mi][ni]);  \
  __builtin_amdgcn_s_setprio(0)

template <int EPI>
__global__ __launch_bounds__(512, 2) void gemm256(const bf16* __restrict__ A, const bf16* __restrict__ B,
                                                  const float* __restrict__ bias, void* __restrict__ Cv,
                                                  const float* __restrict__ extra, int N, int K) {
  __shared__ __align__(16) bf16 L[2][2][2][8192];  // 128 KiB
  const int nbn = N >> 8;
  const int nwg = (int)gridDim.x;
  int wg = (int)blockIdx.x;
  {  // bijective XCD-aware swizzle (m204)
    const int q = nwg >> 3, r = nwg & 7;
    const int xcd = wg & 7, loc = wg >> 3;
    wg = (xcd < r ? xcd * (q + 1) : r * (q + 1) + (xcd - r) * q) + loc;
  }
  const int bm = wg / nbn, bn = wg % nbn;
  const int tid = (int)threadIdx.x;
  const int wave = tid >> 6, lane = tid & 63;
  const int wm2 = wave >> 2, wn4 = wave & 3;       // 2 (M) x 4 (N) wave grid
  const int quad = lane >> 4, l16 = lane & 15;

  // staging source mapping: inverse swizzle of linear dest slot, 2 issues/thread
  const int sl0 = tid, sl1 = 512 + tid;
  const int rp0 = sl0 >> 3, ls0 = (sl0 & 7) ^ (rp0 & 7);
  const int rp1 = sl1 >> 3, ls1 = (sl1 & 7) ^ (rp1 & 7);
  const int row0 = rp0 * 2 + (ls0 >> 2), c0 = ls0 & 3;
  const int row1 = rp1 * 2 + (ls1 >> 2), c1 = ls1 & 3;
  const bf16* pa0 = A + (size_t)(bm * 256 + row0) * K + c0 * 8;
  const bf16* pa1 = A + (size_t)(bm * 256 + row1) * K + c1 * 8;
  const bf16* pb0 = B + (size_t)(bn * 256 + row0) * K + c0 * 8;
  const bf16* pb1 = B + (size_t)(bn * 256 + row1) * K + c1 * 8;

  // ds_read fragment offsets (elems); +512 per 16-row step (swizzle-invariant)
  const int ar = wm2 * 128 + l16, arp = ar >> 1;
  const int aoff = (arp * 8 + ((((ar & 1) << 2) | quad) ^ (arp & 7))) * 8;
  const int br = wn4 * 64 + l16, brp = br >> 1;
  const int boff = (brp * 8 + ((((br & 1) << 2) | quad) ^ (brp & 7))) * 8;

  f32x4 acc[8][4] = {};
  bf16x8 af0[4], af1[4], bfr0[4], bfr1[4];

  // prologue: stage tile 0 -> buf 0, order [A.k0, B.k0, A.k1, B.k1]
  GLDS16(pa0, &L[0][0][0][sl0 * 8]);
  GLDS16(pa1, &L[0][0][0][sl1 * 8]);
  GLDS16(pb0, &L[0][1][0][sl0 * 8]);
  GLDS16(pb1, &L[0][1][0][sl1 * 8]);
  GLDS16(pa0 + 32, &L[0][0][1][sl0 * 8]);
  GLDS16(pa1 + 32, &L[0][0][1][sl1 * 8]);
  GLDS16(pb0 + 32, &L[0][1][1][sl0 * 8]);
  GLDS16(pb1 + 32, &L[0][1][1][sl1 * 8]);
  VMCNT(4);  // A.k0, B.k0 of tile 0 resident (own shares)
  SBAR;      // ... for everyone
  // preload phase-1 regs (8 reads left in flight; ph1 waits lgkm(4) after issuing 4)
  LOAD_A(af0, 0, 0, 0);
  LOAD_B(bfr0, 0, 0);

#pragma unroll 2
  for (int kt = 0; kt < K - 64; kt += 64) {
    const int cb = (kt >> 6) & 1, nb = cb ^ 1;
    const int kn = kt + 64;
    // ---- phase 1 ----
    LOAD_A(af1, cb, 0, 4);
    GLDS16(pa0 + kn, &L[nb][0][0][sl0 * 8]);
    GLDS16(pa1 + kn, &L[nb][0][0][sl1 * 8]);
    LGKM(4);
    MFMAS(0, af0, bfr0);
    VMCNT(2);  // k1(t) resident
    SBAR;
    // ---- phase 2 ----
    LOAD_A(af0, cb, 1, 0);
    LOAD_B(bfr1, cb, 1);
    GLDS16(pb0 + kn, &L[nb][1][0][sl0 * 8]);
    GLDS16(pb1 + kn, &L[nb][1][0][sl1 * 8]);
    LGKM(8);
    MFMAS(4, af1, bfr0);
    SBAR;
    // ---- phase 3 ----
    LOAD_A(af1, cb, 1, 4);
    GLDS16(pa0 + kn + 32, &L[nb][0][1][sl0 * 8]);
    GLDS16(pa1 + kn + 32, &L[nb][0][1][sl1 * 8]);
    LGKM(4);
    MFMAS(0, af0, bfr1);
    VMCNT(2);  // k0(t+1) resident
    SBAR;
    // ---- phase 4 ----
    LOAD_A(af0, nb, 0, 0);
    LOAD_B(bfr0, nb, 0);
    GLDS16(pb0 + kn + 32, &L[nb][1][1][sl0 * 8]);
    GLDS16(pb1 + kn + 32, &L[nb][1][1][sl1 * 8]);
    LGKM(8);
    MFMAS(4, af1, bfr1);
    SBAR;
  }
  // ---- peeled last tile: no staging; single vmcnt(0) drain ----
  {
    const int cb = ((K >> 6) - 1) & 1;
    LOAD_A(af1, cb, 0, 4);
    LGKM(4);
    MFMAS(0, af0, bfr0);
    VMCNT(0);  // k1(last) resident (all staging retired)
    SBAR;
    LOAD_A(af0, cb, 1, 0);
    LOAD_B(bfr1, cb, 1);
    LGKM(8);
    MFMAS(4, af1, bfr0);
    SBAR;
    LOAD_A(af1, cb, 1, 4);
    LGKM(4);
    MFMAS(0, af0, bfr1);
    SBAR;
    LGKM(0);
    MFMAS(4, af1, bfr1);
  }

  // epilogue (transposed acc): thread holds 4 consecutive FEATURES at one token
  bf16* Cb = (bf16*)Cv;
  float* Cf = (float*)Cv;
#pragma unroll
  for (int mi = 0; mi < 8; ++mi) {
    const int row = bm * 256 + wm2 * 128 + mi * 16 + l16;
#pragma unroll
    for (int ni = 0; ni < 4; ++ni) {
      const int colb = bn * 256 + wn4 * 64 + ni * 16 + quad * 4;
      const float4 bq = *(const float4*)(bias + colb);
      const float bbv[4] = {bq.x, bq.y, bq.z, bq.w};
      float v4[4];
#pragma unroll
      for (int r = 0; r < 4; ++r) v4[r] = acc[mi][ni][r] + bbv[r];
      if constexpr (EPI == 1) {
        const int which = colb >> 9, head = (colb >> 5) & 15, d = colb & 31;
        const int win = row >> 6, n = row & 63;
        bf16x4 ov;
#pragma unroll
        for (int r = 0; r < 4; ++r) ov[r] = (bf16)v4[r];
        *(bf16x4*)(Cb + (size_t)which * kQS + (((size_t)win * kHeads + head) * kNt + n) * kHd + d) = ov;
      } else if constexpr (EPI == 2) {
        bf16x4 ov;
#pragma unroll
        for (int r = 0; r < 4; ++r) {
          const float g = 0.5f * v4[r] * (1.f + erff(v4[r] * 0.70710678118654752f));
          ov[r] = (bf16)g;
        }
        *(bf16x4*)(Cb + (size_t)row * N + colb) = ov;
      } else if constexpr (EPI == 3) {
        const float4 ex = *(const float4*)(extra + (size_t)row * N + colb);
        float4 o4 = {v4[0] + ex.x, v4[1] + ex.y, v4[2] + ex.z, v4[3] + ex.w};
        *(float4*)(Cf + (size_t)row * N + colb) = o4;
      } else {  // EPI == 4: window-reverse + roll(+4) + residual
        const int win = row >> 6, n = row & 63;
        const int b = win / kNw, wi = win % kNw;
        const int h0 = ((wi / 7) * 8 + (n >> 3) + 4) % 56;
        const int w0 = ((wi % 7) * 8 + (n & 7) + 4) % 56;
        const size_t dst = ((size_t)b * kL + h0 * 56 + w0) * kDim + colb;
        const float4 ex = *(const float4*)(extra + dst);
        float4 o4 = {v4[0] + ex.x, v4[1] + ex.y, v4[2] + ex.z, v4[3] + ex.w};
        *(float4*)(Cf + dst) = o4;
      }
    }
  }
}

// ---------------- attention: one wave per (window, head) ----------------
__device__ __forceinline__ int reg3(int x) { return x < 48 ? 0 : (x < 52 ? 1 : 2); }

__global__ __launch_bounds__(128) void attn_kernel(const bf16* __restrict__ qkv,
                                                   const float* __restrict__ ptbl,
                                                   bf16* __restrict__ out) {
  __shared__ float Sb[2][64 * 65];
  __shared__ float Rs[2][64];
  __shared__ bf16  Pb[2][64 * 72];
  __shared__ bf16  Vt[2][32 * 72];
  const int w = threadIdx.x >> 6, lane = threadIdx.x & 63;
  const int gwh = blockIdx.x * 2 + w;
  const int win = gwh >> 4, h = gwh & 15;
  const int quad = lane >> 4, l16 = lane & 15;
  const bf16* q = qkv + ((size_t)win * kHeads + h) * (kNt * kHd);
  const bf16* k = q + kQS;
  const bf16* v = q + 2 * kQS;

  // stage V^T (Vt[d][tok], pitch 72)
#pragma unroll
  for (int i = 0; i < 4; ++i) {
    const int row = i * 16 + (lane >> 2);
    const int d0 = (lane & 3) * 8;
    bf16x8 vv = *(const bf16x8*)(v + row * kHd + d0);
#pragma unroll
    for (int j = 0; j < 8; ++j) Vt[w][(d0 + j) * 72 + row] = vv[j];
  }

  // S = Q K^T: hd=32 == MFMA K, frags straight from global
  bf16x8 qf[4], kf[4];
#pragma unroll
  for (int i = 0; i < 4; ++i) qf[i] = *(const bf16x8*)(q + (i * 16 + l16) * kHd + quad * 8);
#pragma unroll
  for (int j = 0; j < 4; ++j) kf[j] = *(const bf16x8*)(k + (j * 16 + l16) * kHd + quad * 8);
  f32x4 sa[4][4] = {};
#pragma unroll
  for (int i = 0; i < 4; ++i)
#pragma unroll
    for (int j = 0; j < 4; ++j) sa[i][j] = MFMA_BF16(qf[i], kf[j], sa[i][j]);

  // scale + pos-bias + shift-mask, write S (fp32, pitch 65 -> conflict-free row reads)
  const int wi = win % kNw;
  const int hb = (wi / 7) * 8, wb = (wi % 7) * 8;
  const float* bh = ptbl + h * 4096;
#pragma unroll
  for (int i = 0; i < 4; ++i) {
#pragma unroll
    for (int j = 0; j < 4; ++j) {
      const int ct = j * 16 + l16;
      const int crg = reg3(hb + (ct >> 3)) * 3 + reg3(wb + (ct & 7));
#pragma unroll
      for (int r = 0; r < 4; ++r) {
        const int rt = i * 16 + quad * 4 + r;
        const int rrg = reg3(hb + (rt >> 3)) * 3 + reg3(wb + (rt & 7));
        float sv = sa[i][j][r] * 0.17677669529663687f + bh[rt * 64 + ct];
        if (rrg != crg) sv -= 100.f;
        Sb[w][rt * 65 + ct] = sv;
      }
    }
  }
  __syncthreads();

  // softmax: one row per lane; store unnormalized P (bf16), normalize O at the end
  float mx = -1e30f;
  for (int i = 0; i < 64; ++i) mx = fmaxf(mx, Sb[w][lane * 65 + i]);
  float sum = 0.f;
  for (int i = 0; i < 64; ++i) {
    const float p = __expf(Sb[w][lane * 65 + i] - mx);
    sum += p;
    Pb[w][lane * 72 + i] = (bf16)p;
  }
  Rs[w][lane] = 1.f / sum;
  __syncthreads();

  // O = P V
  f32x4 oa[4][2] = {};
#pragma unroll
  for (int kk = 0; kk < 2; ++kk) {
    bf16x8 pf[4], vf[2];
#pragma unroll
    for (int mi = 0; mi < 4; ++mi)
      pf[mi] = *(const bf16x8*)(&Pb[w][(mi * 16 + l16) * 72 + kk * 32 + quad * 8]);
#pragma unroll
    for (int nj = 0; nj < 2; ++nj)
      vf[nj] = *(const bf16x8*)(&Vt[w][(nj * 16 + l16) * 72 + kk * 32 + quad * 8]);
#pragma unroll
    for (int mi = 0; mi < 4; ++mi)
#pragma unroll
      for (int nj = 0; nj < 2; ++nj) oa[mi][nj] = MFMA_BF16(pf[mi], vf[nj], oa[mi][nj]);
  }
#pragma unroll
  for (int mi = 0; mi < 4; ++mi)
#pragma unroll
    for (int nj = 0; nj < 2; ++nj)
#pragma unroll
      for (int r = 0; r < 4; ++r) {
        const int row = mi * 16 + quad * 4 + r;
        const int col = nj * 16 + l16;
        out[((size_t)win * kNt + row) * kDim + h * kHd + col] = (bf16)(oa[mi][nj][r] * Rs[w][row]);
      }
}

// ---------------- launch ----------------
extern "C" void kernel_launch(void* const* d_in, const int* in_sizes, int n_in,
                              void* d_out, int out_size, void* d_ws, size_t ws_size,
                              hipStream_t stream) {
  (void)in_sizes; (void)n_in; (void)out_size; (void)ws_size;
  const float* x      = (const float*)d_in[0];
  const float* g1     = (const float*)d_in[1];
  const float* be1    = (const float*)d_in[2];
  const float* w_qkv  = (const float*)d_in[3];
  const float* b_qkv  = (const float*)d_in[4];
  const float* pm_w1  = (const float*)d_in[5];
  const float* pm_b1  = (const float*)d_in[6];
  const float* pm_w2  = (const float*)d_in[7];
  const float* pm_b2  = (const float*)d_in[8];
  const float* w_proj = (const float*)d_in[9];
  const float* b_proj = (const float*)d_in[10];
  const float* g2     = (const float*)d_in[11];
  const float* be2    = (const float*)d_in[12];
  const float* w_fc1  = (const float*)d_in[13];
  const float* b_fc1  = (const float*)d_in[14];
  const float* w_fc2  = (const float*)d_in[15];
  const float* b_fc2  = (const float*)d_in[16];
  float* out = (float*)d_out;
  char* ws = (char*)d_ws;

  // workspace layout (bytes); regions reused across phases
  constexpr size_t OFF_WB   = 1u << 20;                 // bf16 weights (8 MiB region)
  constexpr size_t OFF_XW   = OFF_WB + (8u << 20);      // xw -> attn_out -> xn2 (bf16, 103 MB)
  constexpr size_t SZ_ACT   = (size_t)kToks * kDim * 2;
  constexpr size_t OFF_QKV  = OFF_XW + SZ_ACT;          // qkv bf16 (308 MB) -> x1 fp32 + hbuf bf16
  float* biastbl = (float*)ws;
  bf16* wqb = (bf16*)(ws + OFF_WB);                     // 786432 elems
  bf16* wpb = wqb + 786432;                             // 262144
  bf16* w1b = wpb + 262144;                             // 1048576
  bf16* w2b = w1b + 1048576;                            // 1048576
  bf16* xw    = (bf16*)(ws + OFF_XW);
  bf16* attnb = xw;            // after QKV gemm consumes xw
  bf16* xn2   = xw;            // after proj consumes attnb
  bf16* qkvb = (bf16*)(ws + OFF_QKV);
  float* x1  = (float*)(ws + OFF_QKV);                  // after attn consumes qkv (206 MB)
  bf16* hbuf = (bf16*)(ws + OFF_QKV + (size_t)kToks * kDim * 4);  // 103 MB

  wconv_kernel<<<dim3(786432 / 2048), dim3(256), 0, stream>>>(w_qkv, wqb, 786432 / 8);
  wconv_kernel<<<dim3(262144 / 2048), dim3(256), 0, stream>>>(w_proj, wpb, 262144 / 8);
  wconv_kernel<<<dim3(1048576 / 2048), dim3(256), 0, stream>>>(w_fc1, w1b, 1048576 / 8);
  wconv_kernel<<<dim3(1048576 / 2048), dim3(256), 0, stream>>>(w_fc2, w2b, 1048576 / 8);
  posbias_kernel<<<dim3(256), dim3(256), 0, stream>>>(pm_w1, pm_b1, pm_w2, pm_b2, biastbl);
  ln_kernel<0><<<dim3(kToks / 4), dim3(256), 0, stream>>>(x, g1, be1, xw);
  gemm256<1><<<dim3((kToks / 256) * (1536 / 256)), dim3(512), 0, stream>>>(
      xw, wqb, b_qkv, qkvb, nullptr, 1536, 512);
  attn_kernel<<<dim3(kWins * kHeads / 2), dim3(128), 0, stream>>>(qkvb, biastbl, attnb);
  gemm256<4><<<dim3((kToks / 256) * (512 / 256)), dim3(512), 0, stream>>>(
      attnb, wpb, b_proj, x1, x, 512, 512);
  ln_kernel<1><<<dim3(kToks / 4), dim3(256), 0, stream>>>(x1, g2, be2, xn2);
  constexpr int kChunk = kToks / 4;  // 25088 rows per MLP chunk
  for (int c = 0; c < 4; ++c) {
    const size_t ro = (size_t)c * kChunk * kDim;
    gemm256<2><<<dim3((kChunk / 256) * (kHid / 256)), dim3(512), 0, stream>>>(
        xn2 + ro, w1b, b_fc1, hbuf, nullptr, kHid, 512);
    gemm256<3><<<dim3((kChunk / 256) * (512 / 256)), dim3(512), 0, stream>>>(
        hbuf, w2b, b_fc2, out + ro, x1 + ro, 512, kHid);
  }
}

// Round 5
// 1627.391 us; speedup vs baseline: 1.0344x; 1.0285x over previous
//
#include <hip/hip_runtime.h>
#include <math.h>

typedef __bf16 bf16;
typedef bf16 bf16x4 __attribute__((ext_vector_type(4)));
typedef bf16 bf16x8 __attribute__((ext_vector_type(8)));
typedef float f32x4 __attribute__((ext_vector_type(4)));

#define MFMA_BF16(a, b, c) __builtin_amdgcn_mfma_f32_16x16x32_bf16((a), (b), (c), 0, 0, 0)
#define GLDS16(gp, lp)                                                            \
  __builtin_amdgcn_global_load_lds((__attribute__((address_space(1))) void*)(gp), \
                                   (__attribute__((address_space(3))) void*)(lp), 16, 0, 0)
#define VMCNT(N) asm volatile("s_waitcnt vmcnt(" #N ")" ::: "memory")
#define LGKM(N) asm volatile("s_waitcnt lgkmcnt(" #N ")" ::: "memory")
#define SBAR __builtin_amdgcn_s_barrier()
#define SCHED0 __builtin_amdgcn_sched_barrier(0)

static constexpr int kDim   = 512;
static constexpr int kHeads = 16;
static constexpr int kHd    = 32;
static constexpr int kNt    = 64;    // tokens per window (8*8)
static constexpr int kNw    = 49;    // windows per image (7*7)
static constexpr int kL     = 3136;  // 56*56
static constexpr int kToks  = 100352;
static constexpr int kWins  = 1568;
static constexpr int kHid   = 2048;
static constexpr size_t kQS = (size_t)kWins * kHeads * kNt * kHd;  // elems per q/k/v

// ---------------- fp32 -> bf16 weight conversion ----------------
__global__ __launch_bounds__(256) void wconv_kernel(const float* __restrict__ s,
                                                    bf16* __restrict__ d, int n8) {
  int i = blockIdx.x * 256 + threadIdx.x;
  if (i >= n8) return;
  const float4 a = *(const float4*)(s + i * 8);
  const float4 b = *(const float4*)(s + i * 8 + 4);
  bf16x8 o;
  o[0] = (bf16)a.x; o[1] = (bf16)a.y; o[2] = (bf16)a.z; o[3] = (bf16)a.w;
  o[4] = (bf16)b.x; o[5] = (bf16)b.y; o[6] = (bf16)b.z; o[7] = (bf16)b.w;
  *(bf16x8*)(d + i * 8) = o;
}

// ---------------- pos-bias table: (16, 64, 64) fp32 ----------------
__global__ void posbias_kernel(const float* __restrict__ w1, const float* __restrict__ b1,
                               const float* __restrict__ w2, const float* __restrict__ b2,
                               float* __restrict__ tbl) {
  int idx = blockIdx.x * 256 + threadIdx.x;
  if (idx >= kHeads * kNt * kNt) return;
  int h = idx >> 12, n = (idx >> 6) & 63, m = idx & 63;
  float dr = (float)((n >> 3) - (m >> 3));
  float dc = (float)((n & 7) - (m & 7));
  dr = (dr > 0.f ? 1.f : (dr < 0.f ? -1.f : 0.f)) * log1pf(fabsf(dr));
  dc = (dc > 0.f ? 1.f : (dc < 0.f ? -1.f : 0.f)) * log1pf(fabsf(dc));
  float acc = b2[h];
  for (int o = 0; o < 32; ++o) {
    float hv = w1[o * 2] * dr + w1[o * 2 + 1] * dc + b1[o];
    acc += w2[h * 32 + o] * fmaxf(hv, 0.f);
  }
  tbl[idx] = acc;
}

// ---------------- LayerNorm (fp32 in, bf16 out), one wave per token ----------------
// MODE 0: gather (roll -4,-4 + window partition) from x -> xw (window-token order)
// MODE 1: identity token order
template <int MODE>
__global__ __launch_bounds__(256) void ln_kernel(const float* __restrict__ x,
                                                 const float* __restrict__ g,
                                                 const float* __restrict__ be,
                                                 bf16* __restrict__ o) {
  const int t = blockIdx.x * 4 + (threadIdx.x >> 6);
  const int lane = threadIdx.x & 63;
  size_t src;
  if (MODE == 0) {
    const int win = t >> 6, n = t & 63;
    const int b = win / kNw, wi = win % kNw;
    const int h0 = ((wi / 7) * 8 + (n >> 3) + 4) % 56;   // roll(-4): src = dst+4 mod 56
    const int w0 = ((wi % 7) * 8 + (n & 7) + 4) % 56;
    src = ((size_t)b * kL + h0 * 56 + w0) * kDim;
  } else {
    src = (size_t)t * kDim;
  }
  const float4 a = *(const float4*)(x + src + lane * 8);
  const float4 bq = *(const float4*)(x + src + lane * 8 + 4);
  float xf[8] = {a.x, a.y, a.z, a.w, bq.x, bq.y, bq.z, bq.w};
  float s = 0.f, s2 = 0.f;
#pragma unroll
  for (int j = 0; j < 8; ++j) { s += xf[j]; s2 += xf[j] * xf[j]; }
#pragma unroll
  for (int off = 32; off > 0; off >>= 1) { s += __shfl_xor(s, off); s2 += __shfl_xor(s2, off); }
  const float mean = s * (1.f / 512.f);
  const float rstd = rsqrtf(s2 * (1.f / 512.f) - mean * mean + 1e-5f);
  const float4 ga = *(const float4*)(g + lane * 8);
  const float4 gb = *(const float4*)(g + lane * 8 + 4);
  const float4 ba = *(const float4*)(be + lane * 8);
  const float4 bb = *(const float4*)(be + lane * 8 + 4);
  const float gv[8] = {ga.x, ga.y, ga.z, ga.w, gb.x, gb.y, gb.z, gb.w};
  const float bv[8] = {ba.x, ba.y, ba.z, ba.w, bb.x, bb.y, bb.z, bb.w};
  bf16x8 ov;
#pragma unroll
  for (int j = 0; j < 8; ++j) ov[j] = (bf16)((xf[j] - mean) * rstd * gv[j] + bv[j]);
  *(bf16x8*)(o + (size_t)t * kDim + lane * 8) = ov;
}

// ---------------- GEMM 256x256, BK=64, 8 waves, deep-pipelined ----------------
// C[M,N] = A[M,K] * B[N,K]^T + bias, fused epilogues.
// LDS: [buf][A/B][khalf][256 rows x 32 cols], 16B slots XOR-swizzled; staging is
// linear-dest global_load_lds with inverse swizzle on the global source address.
// R5: staging stream SHIFTED 2 phases earlier so every GLDS has >=2 phases between
// issue and its vmcnt wait (R3/R4 gave only 1 phase -> loaded-HBM-latency bound).
// Slot order per tile t: ph1->B.k0(t+1), ph2->A.k1(t+1), ph3->B.k1(t+1),
// ph4->A.k0(t+2) into cb (cb.k0 dead after ph1).  Waits: VMCNT(4) at ph1-end
// (publishes k1(t)) and ph3-end (publishes k0(t+1)). Register frags stay one
// phase ahead with counted lgkm (R3).
#define LOAD_A(dst, CB, KH, MB)                                        \
  _Pragma("unroll") for (int i = 0; i < 4; ++i)                        \
      dst[i] = *(const bf16x8*)(&L[CB][0][KH][aoff + (MB + i) * 512]);
#define LOAD_B(dst, CB, KH)                                            \
  _Pragma("unroll") for (int i = 0; i < 4; ++i)                        \
      dst[i] = *(const bf16x8*)(&L[CB][1][KH][boff + i * 512]);
#define MFMAS(MB, AF, BF)                                              \
  SCHED0;                                                              \
  __builtin_amdgcn_s_setprio(1);                                       \
  _Pragma("unroll") for (int mi = 0; mi < 4; ++mi)                     \
  _Pragma("unroll") for (int ni = 0; ni < 4; ++ni)                     \
      acc[MB + mi][ni] = MFMA_BF16(BF[ni], AF[mi], acc[MB + mi][ni]);  \
  __builtin_amdgcn_s_setprio(0)

template <int EPI>
__global__ __launch_bounds__(512, 2) void gemm256(const bf16* __restrict__ A, const bf16* __restrict__ B,
                                                  const float* __restrict__ bias, void* __restrict__ Cv,
                                                  const float* __restrict__ extra, int N, int K) {
  __shared__ __align__(16) bf16 L[2][2][2][8192];  // 128 KiB
  const int nbn = N >> 8;
  const int nwg = (int)gridDim.x;
  int wg = (int)blockIdx.x;
  {  // bijective XCD-aware swizzle (m204)
    const int q = nwg >> 3, r = nwg & 7;
    const int xcd = wg & 7, loc = wg >> 3;
    wg = (xcd < r ? xcd * (q + 1) : r * (q + 1) + (xcd - r) * q) + loc;
  }
  const int bm = wg / nbn, bn = wg % nbn;
  const int tid = (int)threadIdx.x;
  const int wave = tid >> 6, lane = tid & 63;
  const int wm2 = wave >> 2, wn4 = wave & 3;       // 2 (M) x 4 (N) wave grid
  const int quad = lane >> 4, l16 = lane & 15;

  // staging source mapping: inverse swizzle of linear dest slot, 2 issues/thread
  const int sl0 = tid, sl1 = 512 + tid;
  const int rp0 = sl0 >> 3, ls0 = (sl0 & 7) ^ (rp0 & 7);
  const int rp1 = sl1 >> 3, ls1 = (sl1 & 7) ^ (rp1 & 7);
  const int row0 = rp0 * 2 + (ls0 >> 2), c0 = ls0 & 3;
  const int row1 = rp1 * 2 + (ls1 >> 2), c1 = ls1 & 3;
  const bf16* pa0 = A + (size_t)(bm * 256 + row0) * K + c0 * 8;
  const bf16* pa1 = A + (size_t)(bm * 256 + row1) * K + c1 * 8;
  const bf16* pb0 = B + (size_t)(bn * 256 + row0) * K + c0 * 8;
  const bf16* pb1 = B + (size_t)(bn * 256 + row1) * K + c1 * 8;

  // ds_read fragment offsets (elems); +512 per 16-row step (swizzle-invariant)
  const int ar = wm2 * 128 + l16, arp = ar >> 1;
  const int aoff = (arp * 8 + ((((ar & 1) << 2) | quad) ^ (arp & 7))) * 8;
  const int br = wn4 * 64 + l16, brp = br >> 1;
  const int boff = (brp * 8 + ((((br & 1) << 2) | quad) ^ (brp & 7))) * 8;

  f32x4 acc[8][4] = {};
  bf16x8 af0[4], af1[4], bfr0[4], bfr1[4];

  // prologue: tile 0 -> buf0 [A.k0,B.k0,A.k1,B.k1], plus A.k0(1) -> buf1
  GLDS16(pa0, &L[0][0][0][sl0 * 8]);
  GLDS16(pa1, &L[0][0][0][sl1 * 8]);
  GLDS16(pb0, &L[0][1][0][sl0 * 8]);
  GLDS16(pb1, &L[0][1][0][sl1 * 8]);
  GLDS16(pa0 + 32, &L[0][0][1][sl0 * 8]);
  GLDS16(pa1 + 32, &L[0][0][1][sl1 * 8]);
  GLDS16(pb0 + 32, &L[0][1][1][sl0 * 8]);
  GLDS16(pb1 + 32, &L[0][1][1][sl1 * 8]);
  GLDS16(pa0 + 64, &L[1][0][0][sl0 * 8]);
  GLDS16(pa1 + 64, &L[1][0][0][sl1 * 8]);
  VMCNT(6);  // A.k0(0), B.k0(0) resident
  SBAR;
  // preload phase-1 regs (8 reads; ph1 waits lgkm(4) after issuing 4 more)
  LOAD_A(af0, 0, 0, 0);
  LOAD_B(bfr0, 0, 0);

#pragma unroll 2
  for (int kt = 0; kt < K; kt += 64) {
    const int cb = (kt >> 6) & 1, nb = cb ^ 1;
    const int kn  = (kt + 64  < K) ? kt + 64  : kt;  // tile t+1 src (clamped: dead at tail)
    const int kn2 = (kt + 128 < K) ? kt + 128 : kt;  // tile t+2 src (clamped)
    // ---- phase 1: MFMA k0.mlo ; stage B.k0(t+1) ----
    LOAD_A(af1, cb, 0, 4);
    GLDS16(pb0 + kn, &L[nb][1][0][sl0 * 8]);
    GLDS16(pb1 + kn, &L[nb][1][0][sl1 * 8]);
    LGKM(4);
    MFMAS(0, af0, bfr0);
    VMCNT(4);  // A.k1(t), B.k1(t) resident
    SBAR;
    // ---- phase 2: MFMA k0.mhi ; stage A.k1(t+1) ----
    LOAD_A(af0, cb, 1, 0);
    LOAD_B(bfr1, cb, 1);
    GLDS16(pa0 + kn + 32, &L[nb][0][1][sl0 * 8]);
    GLDS16(pa1 + kn + 32, &L[nb][0][1][sl1 * 8]);
    LGKM(8);
    MFMAS(4, af1, bfr0);
    SBAR;
    // ---- phase 3: MFMA k1.mlo ; stage B.k1(t+1) ----
    LOAD_A(af1, cb, 1, 4);
    GLDS16(pb0 + kn + 32, &L[nb][1][1][sl0 * 8]);
    GLDS16(pb1 + kn + 32, &L[nb][1][1][sl1 * 8]);
    LGKM(4);
    MFMAS(0, af0, bfr1);
    VMCNT(4);  // A.k0(t+1), B.k0(t+1) resident
    SBAR;
    // ---- phase 4: MFMA k1.mhi ; stage A.k0(t+2) into cb (k0 region dead) ----
    LOAD_A(af0, nb, 0, 0);
    LOAD_B(bfr0, nb, 0);
    GLDS16(pa0 + kn2, &L[cb][0][0][sl0 * 8]);
    GLDS16(pa1 + kn2, &L[cb][0][0][sl1 * 8]);
    LGKM(8);
    MFMAS(4, af1, bfr1);
    SBAR;
  }

  // epilogue (transposed acc): thread holds 4 consecutive FEATURES at one token
  bf16* Cb = (bf16*)Cv;
  float* Cf = (float*)Cv;
#pragma unroll
  for (int mi = 0; mi < 8; ++mi) {
    const int row = bm * 256 + wm2 * 128 + mi * 16 + l16;
#pragma unroll
    for (int ni = 0; ni < 4; ++ni) {
      const int colb = bn * 256 + wn4 * 64 + ni * 16 + quad * 4;
      const float4 bq = *(const float4*)(bias + colb);
      const float bbv[4] = {bq.x, bq.y, bq.z, bq.w};
      float v4[4];
#pragma unroll
      for (int r = 0; r < 4; ++r) v4[r] = acc[mi][ni][r] + bbv[r];
      if constexpr (EPI == 1) {
        const int which = colb >> 9, head = (colb >> 5) & 15, d = colb & 31;
        const int win = row >> 6, n = row & 63;
        bf16x4 ov;
#pragma unroll
        for (int r = 0; r < 4; ++r) ov[r] = (bf16)v4[r];
        *(bf16x4*)(Cb + (size_t)which * kQS + (((size_t)win * kHeads + head) * kNt + n) * kHd + d) = ov;
      } else if constexpr (EPI == 2) {
        bf16x4 ov;
#pragma unroll
        for (int r = 0; r < 4; ++r) {
          const float g = 0.5f * v4[r] * (1.f + erff(v4[r] * 0.70710678118654752f));
          ov[r] = (bf16)g;
        }
        *(bf16x4*)(Cb + (size_t)row * N + colb) = ov;
      } else if constexpr (EPI == 3) {
        const float4 ex = *(const float4*)(extra + (size_t)row * N + colb);
        float4 o4 = {v4[0] + ex.x, v4[1] + ex.y, v4[2] + ex.z, v4[3] + ex.w};
        *(float4*)(Cf + (size_t)row * N + colb) = o4;
      } else {  // EPI == 4: window-reverse + roll(+4) + residual
        const int win = row >> 6, n = row & 63;
        const int b = win / kNw, wi = win % kNw;
        const int h0 = ((wi / 7) * 8 + (n >> 3) + 4) % 56;
        const int w0 = ((wi % 7) * 8 + (n & 7) + 4) % 56;
        const size_t dst = ((size_t)b * kL + h0 * 56 + w0) * kDim + colb;
        const float4 ex = *(const float4*)(extra + dst);
        float4 o4 = {v4[0] + ex.x, v4[1] + ex.y, v4[2] + ex.z, v4[3] + ex.w};
        *(float4*)(Cf + dst) = o4;
      }
    }
  }
}

// ---------------- attention: one wave per (window, head) ----------------
__device__ __forceinline__ int reg3(int x) { return x < 48 ? 0 : (x < 52 ? 1 : 2); }

__global__ __launch_bounds__(128) void attn_kernel(const bf16* __restrict__ qkv,
                                                   const float* __restrict__ ptbl,
                                                   bf16* __restrict__ out) {
  __shared__ float Sb[2][64 * 65];
  __shared__ float Rs[2][64];
  __shared__ bf16  Pb[2][64 * 72];
  __shared__ bf16  Vt[2][32 * 72];
  const int w = threadIdx.x >> 6, lane = threadIdx.x & 63;
  const int gwh = blockIdx.x * 2 + w;
  const int win = gwh >> 4, h = gwh & 15;
  const int quad = lane >> 4, l16 = lane & 15;
  const bf16* q = qkv + ((size_t)win * kHeads + h) * (kNt * kHd);
  const bf16* k = q + kQS;
  const bf16* v = q + 2 * kQS;

  // stage V^T (Vt[d][tok], pitch 72)
#pragma unroll
  for (int i = 0; i < 4; ++i) {
    const int row = i * 16 + (lane >> 2);
    const int d0 = (lane & 3) * 8;
    bf16x8 vv = *(const bf16x8*)(v + row * kHd + d0);
#pragma unroll
    for (int j = 0; j < 8; ++j) Vt[w][(d0 + j) * 72 + row] = vv[j];
  }

  // S = Q K^T: hd=32 == MFMA K, frags straight from global
  bf16x8 qf[4], kf[4];
#pragma unroll
  for (int i = 0; i < 4; ++i) qf[i] = *(const bf16x8*)(q + (i * 16 + l16) * kHd + quad * 8);
#pragma unroll
  for (int j = 0; j < 4; ++j) kf[j] = *(const bf16x8*)(k + (j * 16 + l16) * kHd + quad * 8);
  f32x4 sa[4][4] = {};
#pragma unroll
  for (int i = 0; i < 4; ++i)
#pragma unroll
    for (int j = 0; j < 4; ++j) sa[i][j] = MFMA_BF16(qf[i], kf[j], sa[i][j]);

  // scale + pos-bias + shift-mask, write S (fp32, pitch 65 -> conflict-free row reads)
  const int wi = win % kNw;
  const int hb = (wi / 7) * 8, wb = (wi % 7) * 8;
  const float* bh = ptbl + h * 4096;
#pragma unroll
  for (int i = 0; i < 4; ++i) {
#pragma unroll
    for (int j = 0; j < 4; ++j) {
      const int ct = j * 16 + l16;
      const int crg = reg3(hb + (ct >> 3)) * 3 + reg3(wb + (ct & 7));
#pragma unroll
      for (int r = 0; r < 4; ++r) {
        const int rt = i * 16 + quad * 4 + r;
        const int rrg = reg3(hb + (rt >> 3)) * 3 + reg3(wb + (rt & 7));
        float sv = sa[i][j][r] * 0.17677669529663687f + bh[rt * 64 + ct];
        if (rrg != crg) sv -= 100.f;
        Sb[w][rt * 65 + ct] = sv;
      }
    }
  }
  __syncthreads();

  // softmax: one row per lane; store unnormalized P (bf16), normalize O at the end
  float mx = -1e30f;
  for (int i = 0; i < 64; ++i) mx = fmaxf(mx, Sb[w][lane * 65 + i]);
  float sum = 0.f;
  for (int i = 0; i < 64; ++i) {
    const float p = __expf(Sb[w][lane * 65 + i] - mx);
    sum += p;
    Pb[w][lane * 72 + i] = (bf16)p;
  }
  Rs[w][lane] = 1.f / sum;
  __syncthreads();

  // O = P V
  f32x4 oa[4][2] = {};
#pragma unroll
  for (int kk = 0; kk < 2; ++kk) {
    bf16x8 pf[4], vf[2];
#pragma unroll
    for (int mi = 0; mi < 4; ++mi)
      pf[mi] = *(const bf16x8*)(&Pb[w][(mi * 16 + l16) * 72 + kk * 32 + quad * 8]);
#pragma unroll
    for (int nj = 0; nj < 2; ++nj)
      vf[nj] = *(const bf16x8*)(&Vt[w][(nj * 16 + l16) * 72 + kk * 32 + quad * 8]);
#pragma unroll
    for (int mi = 0; mi < 4; ++mi)
#pragma unroll
      for (int nj = 0; nj < 2; ++nj) oa[mi][nj] = MFMA_BF16(pf[mi], vf[nj], oa[mi][nj]);
  }
#pragma unroll
  for (int mi = 0; mi < 4; ++mi)
#pragma unroll
    for (int nj = 0; nj < 2; ++nj)
#pragma unroll
      for (int r = 0; r < 4; ++r) {
        const int row = mi * 16 + quad * 4 + r;
        const int col = nj * 16 + l16;
        out[((size_t)win * kNt + row) * kDim + h * kHd + col] = (bf16)(oa[mi][nj][r] * Rs[w][row]);
      }
}

// ---------------- launch ----------------
extern "C" void kernel_launch(void* const* d_in, const int* in_sizes, int n_in,
                              void* d_out, int out_size, void* d_ws, size_t ws_size,
                              hipStream_t stream) {
  (void)in_sizes; (void)n_in; (void)out_size; (void)ws_size;
  const float* x      = (const float*)d_in[0];
  const float* g1     = (const float*)d_in[1];
  const float* be1    = (const float*)d_in[2];
  const float* w_qkv  = (const float*)d_in[3];
  const float* b_qkv  = (const float*)d_in[4];
  const float* pm_w1  = (const float*)d_in[5];
  const float* pm_b1  = (const float*)d_in[6];
  const float* pm_w2  = (const float*)d_in[7];
  const float* pm_b2  = (const float*)d_in[8];
  const float* w_proj = (const float*)d_in[9];
  const float* b_proj = (const float*)d_in[10];
  const float* g2     = (const float*)d_in[11];
  const float* be2    = (const float*)d_in[12];
  const float* w_fc1  = (const float*)d_in[13];
  const float* b_fc1  = (const float*)d_in[14];
  const float* w_fc2  = (const float*)d_in[15];
  const float* b_fc2  = (const float*)d_in[16];
  float* out = (float*)d_out;
  char* ws = (char*)d_ws;

  // workspace layout (bytes); regions reused across phases
  constexpr size_t OFF_WB   = 1u << 20;                 // bf16 weights (8 MiB region)
  constexpr size_t OFF_XW   = OFF_WB + (8u << 20);      // xw -> attn_out -> xn2 (bf16, 103 MB)
  constexpr size_t SZ_ACT   = (size_t)kToks * kDim * 2;
  constexpr size_t OFF_QKV  = OFF_XW + SZ_ACT;          // qkv bf16 (308 MB) -> x1 fp32 + hbuf bf16
  float* biastbl = (float*)ws;
  bf16* wqb = (bf16*)(ws + OFF_WB);                     // 786432 elems
  bf16* wpb = wqb + 786432;                             // 262144
  bf16* w1b = wpb + 262144;                             // 1048576
  bf16* w2b = w1b + 1048576;                            // 1048576
  bf16* xw    = (bf16*)(ws + OFF_XW);
  bf16* attnb = xw;            // after QKV gemm consumes xw
  bf16* xn2   = xw;            // after proj consumes attnb
  bf16* qkvb = (bf16*)(ws + OFF_QKV);
  float* x1  = (float*)(ws + OFF_QKV);                  // after attn consumes qkv (206 MB)
  bf16* hbuf = (bf16*)(ws + OFF_QKV + (size_t)kToks * kDim * 4);  // 103 MB

  wconv_kernel<<<dim3(786432 / 2048), dim3(256), 0, stream>>>(w_qkv, wqb, 786432 / 8);
  wconv_kernel<<<dim3(262144 / 2048), dim3(256), 0, stream>>>(w_proj, wpb, 262144 / 8);
  wconv_kernel<<<dim3(1048576 / 2048), dim3(256), 0, stream>>>(w_fc1, w1b, 1048576 / 8);
  wconv_kernel<<<dim3(1048576 / 2048), dim3(256), 0, stream>>>(w_fc2, w2b, 1048576 / 8);
  posbias_kernel<<<dim3(256), dim3(256), 0, stream>>>(pm_w1, pm_b1, pm_w2, pm_b2, biastbl);
  ln_kernel<0><<<dim3(kToks / 4), dim3(256), 0, stream>>>(x, g1, be1, xw);
  gemm256<1><<<dim3((kToks / 256) * (1536 / 256)), dim3(512), 0, stream>>>(
      xw, wqb, b_qkv, qkvb, nullptr, 1536, 512);
  attn_kernel<<<dim3(kWins * kHeads / 2), dim3(128), 0, stream>>>(qkvb, biastbl, attnb);
  gemm256<4><<<dim3((kToks / 256) * (512 / 256)), dim3(512), 0, stream>>>(
      attnb, wpb, b_proj, x1, x, 512, 512);
  ln_kernel<1><<<dim3(kToks / 4), dim3(256), 0, stream>>>(x1, g2, be2, xn2);
  constexpr int kChunk = kToks / 4;  // 25088 rows per MLP chunk
  for (int c = 0; c < 4; ++c) {
    const size_t ro = (size_t)c * kChunk * kDim;
    gemm256<2><<<dim3((kChunk / 256) * (kHid / 256)), dim3(512), 0, stream>>>(
        xn2 + ro, w1b, b_fc1, hbuf, nullptr, kHid, 512);
    gemm256<3><<<dim3((kChunk / 256) * (512 / 256)), dim3(512), 0, stream>>>(
        hbuf, w2b, b_fc2, out + ro, x1 + ro, 512, kHid);
  }
}